// Round 2
// baseline (1105.560 us; speedup 1.0000x reference)
//
#include <hip/hip_runtime.h>

#define N_NODES 100000
#define N_EDGES 500000
#define N_GRAPHS 64
#define IN_DIM 512
#define HID 256
#define NREL 16

using short8 = __attribute__((ext_vector_type(8))) short;
using f32x4  = __attribute__((ext_vector_type(4))) float;

__device__ __forceinline__ unsigned short f2bf(float f) {
    union { float f; unsigned u; } v; v.f = f;
    unsigned u = v.u;
    unsigned r = u + 0x7FFF + ((u >> 16) & 1);
    return (unsigned short)(r >> 16);
}
__device__ __forceinline__ float bf2f(unsigned short h) {
    union { unsigned u; float f; } v; v.u = ((unsigned)h) << 16;
    return v.f;
}

__device__ __forceinline__ void gload_lds16(const unsigned short* g, unsigned short* l) {
    __builtin_amdgcn_global_load_lds(
        (const __attribute__((address_space(1))) void*)(g),
        (__attribute__((address_space(3))) void*)(l), 16, 0, 0);
}

// ---------------- conversions ----------------
__global__ void k_f2bf(const float* __restrict__ in, unsigned short* __restrict__ out, int n8) {
    int i = blockIdx.x * 256 + threadIdx.x;
    if (i >= n8) return;
    const float4* p = (const float4*)in + (size_t)i * 2;
    float4 a = p[0], b = p[1];
    ushort4 u0, u1;
    u0.x = f2bf(a.x); u0.y = f2bf(a.y); u0.z = f2bf(a.z); u0.w = f2bf(a.w);
    u1.x = f2bf(b.x); u1.y = f2bf(b.y); u1.z = f2bf(b.z); u1.w = f2bf(b.w);
    ushort4* q = (ushort4*)out + (size_t)i * 2;
    q[0] = u0; q[1] = u1;
}

// Wt[n][k] = bf16( n<HID ? Wrel[k][n] : Wroot[k][n-HID] ), n in [0,512)
__global__ void k_makeWt(const float* __restrict__ Wrel, const float* __restrict__ Wroot,
                         unsigned short* __restrict__ Wt, int K) {
    int n = blockIdx.x;
    const float* Wsrc = (n < HID) ? Wrel : Wroot;
    int col = n & (HID - 1);
    for (int k = threadIdx.x; k < K; k += 256)
        Wt[(size_t)n * K + k] = f2bf(Wsrc[(size_t)k * HID + col]);
}

// WeT[r][k] = bf16(W_edge[k][r]), r<16, k<512
__global__ void k_makeWeT(const float* __restrict__ We, unsigned short* __restrict__ WeT) {
    int idx = blockIdx.x * 256 + threadIdx.x;
    if (idx >= NREL * 2 * HID) return;
    int r = idx >> 9, k = idx & 511;
    WeT[idx] = f2bf(We[k * NREL + r]);
}

// ---------------- CSR build ----------------
__global__ void k_hist(const int* __restrict__ dstArr, int* __restrict__ counts) {
    int i = blockIdx.x * 256 + threadIdx.x;
    if (i < N_EDGES) atomicAdd(&counts[dstArr[i]], 1);
}

__global__ void k_scanA(const int* __restrict__ counts, int* __restrict__ bsum) {
    __shared__ int ws[4];
    int i = blockIdx.x * 256 + threadIdx.x;
    int v = (i < N_NODES) ? counts[i] : 0;
    for (int o = 32; o; o >>= 1) v += __shfl_down(v, o, 64);
    if ((threadIdx.x & 63) == 0) ws[threadIdx.x >> 6] = v;
    __syncthreads();
    if (threadIdx.x == 0) bsum[blockIdx.x] = ws[0] + ws[1] + ws[2] + ws[3];
}

__global__ void k_scanB(int* __restrict__ bsum, int nb) {
    __shared__ int buf[512];
    int t = threadIdx.x;
    for (int i = t; i < nb; i += 256) buf[i] = bsum[i];
    __syncthreads();
    if (t == 0) { int s = 0; for (int i = 0; i < nb; ++i) { int x = buf[i]; buf[i] = s; s += x; } }
    __syncthreads();
    for (int i = t; i < nb; i += 256) bsum[i] = buf[i];
}

__global__ void k_scanC(const int* __restrict__ counts, const int* __restrict__ bsum,
                        int* __restrict__ offsets) {
    __shared__ int ws[4];
    int i = blockIdx.x * 256 + threadIdx.x;
    int lane = threadIdx.x & 63, wid = threadIdx.x >> 6;
    int v = (i < N_NODES) ? counts[i] : 0;
    int x = v;
    for (int o = 1; o < 64; o <<= 1) { int u = __shfl_up(x, o, 64); if (lane >= o) x += u; }
    if (lane == 63) ws[wid] = x;
    __syncthreads();
    if (threadIdx.x == 0) { int s = 0; for (int t = 0; t < 4; ++t) { int tt = ws[t]; ws[t] = s; s += tt; } }
    __syncthreads();
    x += ws[wid];
    x += bsum[blockIdx.x];
    if (i < N_NODES) offsets[i + 1] = x;
    if (i == 0) offsets[0] = 0;
}

__global__ void k_fill(const int* __restrict__ srcArr, const int* __restrict__ dstArr,
                       int* __restrict__ cur, int* __restrict__ csr) {
    int i = blockIdx.x * 256 + threadIdx.x;
    if (i < N_EDGES) {
        int p = atomicAdd(&cur[dstArr[i]], 1);
        csr[p] = srcArr[i];
    }
}

// ---------------- GEMM: C[M x 512] = A[M x K](bf16) @ Bt[512 x K](bf16)^T ----------------
__global__ __launch_bounds__(256) void k_gemm(const unsigned short* __restrict__ A,
                                              const unsigned short* __restrict__ Bt,
                                              float* __restrict__ C, int M, int K) {
    __shared__ unsigned short lds[2 * 128 * 64];
    const int tid  = threadIdx.x;
    const int lane = tid & 63;
    const int w    = tid >> 6;
    const int wm   = w >> 1, wn = w & 1;

    // bijective XCD swizzle (nwg % 8 == 0)
    int nwg  = gridDim.x;
    int orig = blockIdx.x;
    int q    = nwg >> 3;
    int id   = (orig & 7) * q + (orig >> 3);
    int bm0  = (id >> 2) * 128;
    int bn0  = (id & 3) * 128;

    f32x4 acc[4][4] = {};

    const int nkt = K >> 6;
    for (int kt = 0; kt < nkt; ++kt) {
        int k0 = kt << 6;
        // stage A tile [128][64] (XOR-swizzled source, linear LDS dest)
        #pragma unroll
        for (int it = 0; it < 4; ++it) {
            int c = (it << 8) + tid;
            int row = c >> 3, kcp = c & 7;
            int kcl = kcp ^ (row & 7);
            int gr = bm0 + row; gr = (gr < M) ? gr : (M - 1);
            gload_lds16(A + (size_t)gr * K + k0 + kcl * 8,
                        &lds[(size_t)((it << 8) + (w << 6)) * 8]);
        }
        // stage B tile [128][64]
        #pragma unroll
        for (int it = 0; it < 4; ++it) {
            int c = (it << 8) + tid;
            int row = c >> 3, kcp = c & 7;
            int kcl = kcp ^ (row & 7);
            gload_lds16(Bt + (size_t)(bn0 + row) * K + k0 + kcl * 8,
                        &lds[128 * 64 + (size_t)((it << 8) + (w << 6)) * 8]);
        }
        __syncthreads();
        #pragma unroll
        for (int kk = 0; kk < 2; ++kk) {
            short8 af[4], bfr[4];
            #pragma unroll
            for (int m = 0; m < 4; ++m) {
                int row = wm * 64 + m * 16 + (lane & 15);
                int kcp = ((kk << 2) + (lane >> 4)) ^ (row & 7);
                af[m] = *(const short8*)&lds[row * 64 + kcp * 8];
            }
            #pragma unroll
            for (int n = 0; n < 4; ++n) {
                int row = wn * 64 + n * 16 + (lane & 15);
                int kcp = ((kk << 2) + (lane >> 4)) ^ (row & 7);
                bfr[n] = *(const short8*)&lds[128 * 64 + row * 64 + kcp * 8];
            }
            #pragma unroll
            for (int m = 0; m < 4; ++m)
                #pragma unroll
                for (int n = 0; n < 4; ++n)
                    acc[m][n] = __builtin_amdgcn_mfma_f32_16x16x32_bf16(af[m], bfr[n], acc[m][n], 0, 0, 0);
        }
        __syncthreads();
    }
    // epilogue: D row=(lane>>4)*4+i, col=lane&15
    #pragma unroll
    for (int m = 0; m < 4; ++m) {
        int row0 = bm0 + wm * 64 + m * 16 + ((lane >> 4) << 2);
        #pragma unroll
        for (int n = 0; n < 4; ++n) {
            int col = bn0 + wn * 64 + n * 16 + (lane & 15);
            #pragma unroll
            for (int i = 0; i < 4; ++i) {
                int r = row0 + i;
                if (r < M) C[(size_t)r * 512 + col] = acc[m][n][i];
            }
        }
    }
}

// ---------------- fused aggregate + root + bias + ReLU -> bf16 ----------------
// y: [N][512] fp32, cols 0..255 = x@W_rel, 256..511 = x@W_root
__global__ void k_combine(const float* __restrict__ y, const int* __restrict__ offs,
                          const int* __restrict__ csr, const float* __restrict__ bias,
                          unsigned short* __restrict__ xout) {
    int node = blockIdx.x * 4 + (threadIdx.x >> 6);
    if (node >= N_NODES) return;
    int lane = threadIdx.x & 63;
    int d = lane * 4;
    float ax = 0.f, ay = 0.f, az = 0.f, aw = 0.f;
    int j0 = offs[node], j1 = offs[node + 1];
    for (int j = j0; j < j1; ++j) {
        int s = csr[j];
        float4 v = *(const float4*)(y + (size_t)s * 512 + d);
        ax += v.x; ay += v.y; az += v.z; aw += v.w;
    }
    float4 r  = *(const float4*)(y + (size_t)node * 512 + 256 + d);
    float4 bb = *(const float4*)(bias + d);
    ushort4 pk;
    pk.x = f2bf(fmaxf(ax + r.x + bb.x, 0.f));
    pk.y = f2bf(fmaxf(ay + r.y + bb.y, 0.f));
    pk.z = f2bf(fmaxf(az + r.z + bb.z, 0.f));
    pk.w = f2bf(fmaxf(aw + r.w + bb.w, 0.f));
    *(ushort4*)(xout + (size_t)node * HID + d) = pk;
}

// ---------------- edge head: gather-GEMM, 16 edges per wave ----------------
__global__ void k_edge(const unsigned short* __restrict__ x,   // [N][256] bf16
                       const unsigned short* __restrict__ WeT, // [16][512] bf16
                       const int* __restrict__ srcArr, const int* __restrict__ dstArr,
                       const float* __restrict__ b_edge, float* __restrict__ out) {
    int lane = threadIdx.x & 63;
    int g = blockIdx.x * 4 + (threadIdx.x >> 6);
    if (g * 16 >= N_EDGES) return;
    short8 bfr[16];
    #pragma unroll
    for (int kk = 0; kk < 16; ++kk)
        bfr[kk] = *(const short8*)&WeT[(size_t)(lane & 15) * 512 + kk * 32 + ((lane >> 4) << 3)];
    int e = g * 16 + (lane & 15);
    if (e >= N_EDGES) e = N_EDGES - 1;
    int s = srcArr[e], d2 = dstArr[e];
    const size_t sb = (size_t)s * HID, db = (size_t)d2 * HID;
    f32x4 acc = {};
    #pragma unroll
    for (int kk = 0; kk < 16; ++kk) {
        int k = kk * 32 + ((lane >> 4) << 3);
        const unsigned short* ap = (k < HID) ? &x[sb + k] : &x[db + k - HID];
        short8 af = *(const short8*)ap;
        acc = __builtin_amdgcn_mfma_f32_16x16x32_bf16(af, bfr[kk], acc, 0, 0, 0);
    }
    float bv = b_edge[lane & 15];
    int col = lane & 15;
    int r0 = g * 16 + ((lane >> 4) << 2);
    #pragma unroll
    for (int i = 0; i < 4; ++i) {
        int row = r0 + i;
        if (row < N_EDGES) out[(size_t)row * NREL + col] = acc[i] + bv;
    }
}

// ---------------- mean pool ----------------
__global__ void k_pool_sum(const unsigned short* __restrict__ x, const int* __restrict__ batch,
                           float* __restrict__ sums) {
    int d = threadIdx.x;
    int n0 = blockIdx.x * 1024;
    int n1 = n0 + 1024; if (n1 > N_NODES) n1 = N_NODES;
    float acc = 0.f;
    int gcur = batch[n0];
    for (int n = n0; n < n1; ++n) {
        int g = batch[n];
        if (g != gcur) { atomicAdd(&sums[gcur * HID + d], acc); acc = 0.f; gcur = g; }
        acc += bf2f(x[(size_t)n * HID + d]);
    }
    atomicAdd(&sums[gcur * HID + d], acc);
}

__device__ __forceinline__ int lowerBound(const int* a, int n, int key) {
    int lo = 0, hi = n;
    while (lo < hi) { int mid = (lo + hi) >> 1; if (a[mid] < key) lo = mid + 1; else hi = mid; }
    return lo;
}

__global__ void k_pool_final(const float* __restrict__ sums, const int* __restrict__ batch,
                             float* __restrict__ out) {
    int g = blockIdx.x, d = threadIdx.x;
    int lo = lowerBound(batch, N_NODES, g);
    int hi = lowerBound(batch, N_NODES, g + 1);
    float cnt = (float)(hi - lo);
    out[(size_t)g * HID + d] = sums[g * HID + d] / fmaxf(cnt, 1.0f);
}

// ---------------- launcher ----------------
extern "C" void kernel_launch(void* const* d_in, const int* in_sizes, int n_in,
                              void* d_out, int out_size, void* d_ws, size_t ws_size,
                              hipStream_t stream) {
    const float* node_feats = (const float*)d_in[0];
    const int*   edge_index = (const int*)d_in[1];
    const int*   batch_idx  = (const int*)d_in[2];
    const float* W_rel0  = (const float*)d_in[3];
    const float* W_root0 = (const float*)d_in[4];
    const float* b0      = (const float*)d_in[5];
    const float* W_rel1  = (const float*)d_in[6];
    const float* W_root1 = (const float*)d_in[7];
    const float* b1      = (const float*)d_in[8];
    const float* W_rel2  = (const float*)d_in[9];
    const float* W_root2 = (const float*)d_in[10];
    const float* b2      = (const float*)d_in[11];
    const float* W_edge  = (const float*)d_in[12];
    const float* b_edge  = (const float*)d_in[13];

    const int* src = edge_index;
    const int* dst = edge_index + N_EDGES;

    char* ws = (char*)d_ws;
    size_t off = 0;
    auto alloc = [&](size_t bytes) -> char* {
        off = (off + 255) & ~(size_t)255;
        char* p = ws + off;
        off += bytes;
        return p;
    };
    unsigned short* bufA = (unsigned short*)alloc((size_t)N_NODES * IN_DIM * 2); // x0b / x2b
    unsigned short* bufB = (unsigned short*)alloc((size_t)N_NODES * HID * 2);    // x1b / x3b
    float*          bufY = (float*)alloc((size_t)N_NODES * 512 * 4);
    unsigned short* Wt0  = (unsigned short*)alloc(512 * 512 * 2);
    unsigned short* Wt1  = (unsigned short*)alloc(512 * 256 * 2);
    unsigned short* Wt2  = (unsigned short*)alloc(512 * 256 * 2);
    unsigned short* WeT  = (unsigned short*)alloc(16 * 512 * 2);
    int* counts  = (int*)alloc((size_t)N_NODES * 4);
    int* offsets = (int*)alloc((size_t)(N_NODES + 1) * 4);
    int* cur     = (int*)alloc((size_t)N_NODES * 4);
    int* csr     = (int*)alloc((size_t)N_EDGES * 4);
    int* bsum    = (int*)alloc(512 * 4);
    float* sums  = (float*)alloc(N_GRAPHS * HID * 4);

    const int nscan = (N_NODES + 255) / 256; // 391

    hipMemsetAsync(counts, 0, (size_t)N_NODES * 4, stream);
    hipMemsetAsync(sums, 0, N_GRAPHS * HID * 4, stream);

    // conversions
    k_f2bf<<<(N_NODES * IN_DIM / 8 + 255) / 256, 256, 0, stream>>>(node_feats, bufA, N_NODES * IN_DIM / 8);
    k_makeWt<<<512, 256, 0, stream>>>(W_rel0, W_root0, Wt0, 512);
    k_makeWt<<<512, 256, 0, stream>>>(W_rel1, W_root1, Wt1, 256);
    k_makeWt<<<512, 256, 0, stream>>>(W_rel2, W_root2, Wt2, 256);
    k_makeWeT<<<32, 256, 0, stream>>>(W_edge, WeT);

    // CSR build
    k_hist<<<(N_EDGES + 255) / 256, 256, 0, stream>>>(dst, counts);
    k_scanA<<<nscan, 256, 0, stream>>>(counts, bsum);
    k_scanB<<<1, 256, 0, stream>>>(bsum, nscan);
    k_scanC<<<nscan, 256, 0, stream>>>(counts, bsum, offsets);
    hipMemcpyAsync(cur, offsets, (size_t)N_NODES * 4, hipMemcpyDeviceToDevice, stream);
    k_fill<<<(N_EDGES + 255) / 256, 256, 0, stream>>>(src, dst, cur, csr);

    const int gemmGrid = ((N_NODES + 127) / 128) * 4; // 782*4 = 3128, %8==0
    // layer 0
    k_gemm<<<gemmGrid, 256, 0, stream>>>(bufA, Wt0, bufY, N_NODES, 512);
    k_combine<<<(N_NODES + 3) / 4, 256, 0, stream>>>(bufY, offsets, csr, b0, bufB);
    // layer 1
    k_gemm<<<gemmGrid, 256, 0, stream>>>(bufB, Wt1, bufY, N_NODES, 256);
    k_combine<<<(N_NODES + 3) / 4, 256, 0, stream>>>(bufY, offsets, csr, b1, bufA);
    // layer 2
    k_gemm<<<gemmGrid, 256, 0, stream>>>(bufA, Wt2, bufY, N_NODES, 256);
    k_combine<<<(N_NODES + 3) / 4, 256, 0, stream>>>(bufY, offsets, csr, b2, bufB);

    // edge head -> d_out[0 : 8M)
    float* out_logits = (float*)d_out;
    k_edge<<<(N_EDGES / 16 + 3) / 4, 256, 0, stream>>>(bufB, WeT, src, dst, b_edge, out_logits);

    // mean pool -> d_out[8M : 8M+16384)
    float* out_embed = (float*)d_out + (size_t)N_EDGES * NREL;
    k_pool_sum<<<(N_NODES + 1023) / 1024, 256, 0, stream>>>(bufB, batch_idx, sums);
    k_pool_final<<<N_GRAPHS, 256, 0, stream>>>(sums, batch_idx, out_embed);
}

// Round 3
// 668.906 us; speedup vs baseline: 1.6528x; 1.6528x over previous
//
#include <hip/hip_runtime.h>

#define N_NODES 100000
#define N_EDGES 500000
#define N_GRAPHS 64
#define IN_DIM 512
#define HID 256
#define NREL 16

using short8 = __attribute__((ext_vector_type(8))) short;
using f32x4  = __attribute__((ext_vector_type(4))) float;

__device__ __forceinline__ unsigned short f2bf(float f) {
    union { float f; unsigned u; } v; v.f = f;
    unsigned u = v.u;
    unsigned r = u + 0x7FFF + ((u >> 16) & 1);
    return (unsigned short)(r >> 16);
}
__device__ __forceinline__ float bf2f(unsigned short h) {
    union { unsigned u; float f; } v; v.u = ((unsigned)h) << 16;
    return v.f;
}

__device__ __forceinline__ void gload_lds16(const unsigned short* g, unsigned short* l) {
    __builtin_amdgcn_global_load_lds(
        (const __attribute__((address_space(1))) void*)(g),
        (__attribute__((address_space(3))) void*)(l), 16, 0, 0);
}

// ---------------- conversions ----------------
__global__ void k_f2bf(const float* __restrict__ in, unsigned short* __restrict__ out, int n8) {
    int i = blockIdx.x * 256 + threadIdx.x;
    if (i >= n8) return;
    const float4* p = (const float4*)in + (size_t)i * 2;
    float4 a = p[0], b = p[1];
    ushort4 u0, u1;
    u0.x = f2bf(a.x); u0.y = f2bf(a.y); u0.z = f2bf(a.z); u0.w = f2bf(a.w);
    u1.x = f2bf(b.x); u1.y = f2bf(b.y); u1.z = f2bf(b.z); u1.w = f2bf(b.w);
    ushort4* q = (ushort4*)out + (size_t)i * 2;
    q[0] = u0; q[1] = u1;
}

// Wt[n][k] = bf16( n<HID ? Wrel[k][n] : Wroot[k][n-HID] ), n in [0,512)
__global__ void k_makeWt(const float* __restrict__ Wrel, const float* __restrict__ Wroot,
                         unsigned short* __restrict__ Wt, int K) {
    int n = blockIdx.x;
    const float* Wsrc = (n < HID) ? Wrel : Wroot;
    int col = n & (HID - 1);
    for (int k = threadIdx.x; k < K; k += 256)
        Wt[(size_t)n * K + k] = f2bf(Wsrc[(size_t)k * HID + col]);
}

// WeT[r][k] = bf16(W_edge[k][r]), r<16, k<512
__global__ void k_makeWeT(const float* __restrict__ We, unsigned short* __restrict__ WeT) {
    int idx = blockIdx.x * 256 + threadIdx.x;
    if (idx >= NREL * 2 * HID) return;
    int r = idx >> 9, k = idx & 511;
    WeT[idx] = f2bf(We[k * NREL + r]);
}

// ---------------- CSR build ----------------
__global__ void k_hist(const int* __restrict__ dstArr, int* __restrict__ counts) {
    int i = blockIdx.x * 256 + threadIdx.x;
    if (i < N_EDGES) atomicAdd(&counts[dstArr[i]], 1);
}

__global__ void k_scanA(const int* __restrict__ counts, int* __restrict__ bsum) {
    __shared__ int ws[4];
    int i = blockIdx.x * 256 + threadIdx.x;
    int v = (i < N_NODES) ? counts[i] : 0;
    for (int o = 32; o; o >>= 1) v += __shfl_down(v, o, 64);
    if ((threadIdx.x & 63) == 0) ws[threadIdx.x >> 6] = v;
    __syncthreads();
    if (threadIdx.x == 0) bsum[blockIdx.x] = ws[0] + ws[1] + ws[2] + ws[3];
}

__global__ void k_scanB(int* __restrict__ bsum, int nb) {
    __shared__ int buf[512];
    int t = threadIdx.x;
    for (int i = t; i < nb; i += 256) buf[i] = bsum[i];
    __syncthreads();
    if (t == 0) { int s = 0; for (int i = 0; i < nb; ++i) { int x = buf[i]; buf[i] = s; s += x; } }
    __syncthreads();
    for (int i = t; i < nb; i += 256) bsum[i] = buf[i];
}

__global__ void k_scanC(const int* __restrict__ counts, const int* __restrict__ bsum,
                        int* __restrict__ offsets) {
    __shared__ int ws[4];
    int i = blockIdx.x * 256 + threadIdx.x;
    int lane = threadIdx.x & 63, wid = threadIdx.x >> 6;
    int v = (i < N_NODES) ? counts[i] : 0;
    int x = v;
    for (int o = 1; o < 64; o <<= 1) { int u = __shfl_up(x, o, 64); if (lane >= o) x += u; }
    if (lane == 63) ws[wid] = x;
    __syncthreads();
    if (threadIdx.x == 0) { int s = 0; for (int t = 0; t < 4; ++t) { int tt = ws[t]; ws[t] = s; s += tt; } }
    __syncthreads();
    x += ws[wid];
    x += bsum[blockIdx.x];
    if (i < N_NODES) offsets[i + 1] = x;
    if (i == 0) offsets[0] = 0;
}

__global__ void k_fill(const int* __restrict__ srcArr, const int* __restrict__ dstArr,
                       int* __restrict__ cur, int* __restrict__ csr) {
    int i = blockIdx.x * 256 + threadIdx.x;
    if (i < N_EDGES) {
        int p = atomicAdd(&cur[dstArr[i]], 1);
        csr[p] = srcArr[i];
    }
}

// ---------------- GEMM: C[M x 512](bf16) = A[M x K](bf16) @ Bt[512 x K](bf16)^T ----------------
__global__ __launch_bounds__(256) void k_gemm(const unsigned short* __restrict__ A,
                                              const unsigned short* __restrict__ Bt,
                                              unsigned short* __restrict__ C, int M, int K) {
    __shared__ unsigned short lds[2 * 128 * 64];
    const int tid  = threadIdx.x;
    const int lane = tid & 63;
    const int w    = tid >> 6;
    const int wm   = w >> 1, wn = w & 1;

    // bijective XCD swizzle (nwg % 8 == 0)
    int nwg  = gridDim.x;
    int orig = blockIdx.x;
    int q    = nwg >> 3;
    int id   = (orig & 7) * q + (orig >> 3);
    int bm0  = (id >> 2) * 128;
    int bn0  = (id & 3) * 128;

    f32x4 acc[4][4] = {};

    const int nkt = K >> 6;
    for (int kt = 0; kt < nkt; ++kt) {
        int k0 = kt << 6;
        // stage A tile [128][64] (XOR-swizzled source, linear LDS dest)
        #pragma unroll
        for (int it = 0; it < 4; ++it) {
            int c = (it << 8) + tid;
            int row = c >> 3, kcp = c & 7;
            int kcl = kcp ^ (row & 7);
            int gr = bm0 + row; gr = (gr < M) ? gr : (M - 1);
            gload_lds16(A + (size_t)gr * K + k0 + kcl * 8,
                        &lds[(size_t)((it << 8) + (w << 6)) * 8]);
        }
        // stage B tile [128][64]
        #pragma unroll
        for (int it = 0; it < 4; ++it) {
            int c = (it << 8) + tid;
            int row = c >> 3, kcp = c & 7;
            int kcl = kcp ^ (row & 7);
            gload_lds16(Bt + (size_t)(bn0 + row) * K + k0 + kcl * 8,
                        &lds[128 * 64 + (size_t)((it << 8) + (w << 6)) * 8]);
        }
        __syncthreads();
        #pragma unroll
        for (int kk = 0; kk < 2; ++kk) {
            short8 af[4], bfr[4];
            #pragma unroll
            for (int m = 0; m < 4; ++m) {
                int row = wm * 64 + m * 16 + (lane & 15);
                int kcp = ((kk << 2) + (lane >> 4)) ^ (row & 7);
                af[m] = *(const short8*)&lds[row * 64 + kcp * 8];
            }
            #pragma unroll
            for (int n = 0; n < 4; ++n) {
                int row = wn * 64 + n * 16 + (lane & 15);
                int kcp = ((kk << 2) + (lane >> 4)) ^ (row & 7);
                bfr[n] = *(const short8*)&lds[128 * 64 + row * 64 + kcp * 8];
            }
            #pragma unroll
            for (int m = 0; m < 4; ++m)
                #pragma unroll
                for (int n = 0; n < 4; ++n)
                    acc[m][n] = __builtin_amdgcn_mfma_f32_16x16x32_bf16(af[m], bfr[n], acc[m][n], 0, 0, 0);
        }
        __syncthreads();
    }
    // epilogue: D row=(lane>>4)*4+i, col=lane&15 ; store bf16
    #pragma unroll
    for (int m = 0; m < 4; ++m) {
        int row0 = bm0 + wm * 64 + m * 16 + ((lane >> 4) << 2);
        #pragma unroll
        for (int n = 0; n < 4; ++n) {
            int col = bn0 + wn * 64 + n * 16 + (lane & 15);
            #pragma unroll
            for (int i = 0; i < 4; ++i) {
                int r = row0 + i;
                if (r < M) C[(size_t)r * 512 + col] = f2bf(acc[m][n][i]);
            }
        }
    }
}

// ---------------- fused aggregate + root + bias + ReLU -> bf16 ----------------
// y: [N][512] bf16, cols 0..255 = x@W_rel, 256..511 = x@W_root
__global__ void k_combine(const unsigned short* __restrict__ y, const int* __restrict__ offs,
                          const int* __restrict__ csr, const float* __restrict__ bias,
                          unsigned short* __restrict__ xout) {
    int node = blockIdx.x * 4 + (threadIdx.x >> 6);
    if (node >= N_NODES) return;
    int lane = threadIdx.x & 63;
    int d = lane * 4;
    float ax = 0.f, ay = 0.f, az = 0.f, aw = 0.f;
    int j0 = offs[node], j1 = offs[node + 1];
    for (int j = j0; j < j1; ++j) {
        int s = csr[j];
        ushort4 v = *(const ushort4*)(y + (size_t)s * 512 + d);
        ax += bf2f(v.x); ay += bf2f(v.y); az += bf2f(v.z); aw += bf2f(v.w);
    }
    ushort4 rr = *(const ushort4*)(y + (size_t)node * 512 + 256 + d);
    float4 bb = *(const float4*)(bias + d);
    ushort4 pk;
    pk.x = f2bf(fmaxf(ax + bf2f(rr.x) + bb.x, 0.f));
    pk.y = f2bf(fmaxf(ay + bf2f(rr.y) + bb.y, 0.f));
    pk.z = f2bf(fmaxf(az + bf2f(rr.z) + bb.z, 0.f));
    pk.w = f2bf(fmaxf(aw + bf2f(rr.w) + bb.w, 0.f));
    *(ushort4*)(xout + (size_t)node * HID + d) = pk;
}

// ---------------- edge head: gather-GEMM, 16 edges per wave ----------------
__global__ void k_edge(const unsigned short* __restrict__ x,   // [N][256] bf16
                       const unsigned short* __restrict__ WeT, // [16][512] bf16
                       const int* __restrict__ srcArr, const int* __restrict__ dstArr,
                       const float* __restrict__ b_edge, float* __restrict__ out) {
    int lane = threadIdx.x & 63;
    int g = blockIdx.x * 4 + (threadIdx.x >> 6);
    if (g * 16 >= N_EDGES) return;
    short8 bfr[16];
    #pragma unroll
    for (int kk = 0; kk < 16; ++kk)
        bfr[kk] = *(const short8*)&WeT[(size_t)(lane & 15) * 512 + kk * 32 + ((lane >> 4) << 3)];
    int e = g * 16 + (lane & 15);
    if (e >= N_EDGES) e = N_EDGES - 1;
    int s = srcArr[e], d2 = dstArr[e];
    const size_t sb = (size_t)s * HID, db = (size_t)d2 * HID;
    f32x4 acc = {};
    #pragma unroll
    for (int kk = 0; kk < 16; ++kk) {
        int k = kk * 32 + ((lane >> 4) << 3);
        const unsigned short* ap = (k < HID) ? &x[sb + k] : &x[db + k - HID];
        short8 af = *(const short8*)ap;
        acc = __builtin_amdgcn_mfma_f32_16x16x32_bf16(af, bfr[kk], acc, 0, 0, 0);
    }
    float bv = b_edge[lane & 15];
    int col = lane & 15;
    int r0 = g * 16 + ((lane >> 4) << 2);
    #pragma unroll
    for (int i = 0; i < 4; ++i) {
        int row = r0 + i;
        if (row < N_EDGES) out[(size_t)row * NREL + col] = acc[i] + bv;
    }
}

// ---------------- mean pool ----------------
// 4 warps/block, each warp owns 32 consecutive nodes; lane covers 4 d's (ushort4).
// Partial sums flushed to sums[] with fp32 atomics at graph boundaries.
__global__ void k_pool_sum(const unsigned short* __restrict__ x, const int* __restrict__ batch,
                           float* __restrict__ sums) {
    const int CH = 32;
    int w = threadIdx.x >> 6, lane = threadIdx.x & 63;
    int n0 = blockIdx.x * (4 * CH) + w * CH;
    if (n0 >= N_NODES) return;
    int n1 = n0 + CH; if (n1 > N_NODES) n1 = N_NODES;
    int d = lane * 4;
    float a0 = 0.f, a1 = 0.f, a2 = 0.f, a3 = 0.f;
    int gcur = batch[n0];
    for (int n = n0; n < n1; ++n) {
        int g = batch[n];
        if (g != gcur) {
            float* p = &sums[gcur * HID + d];
            atomicAdd(p + 0, a0); atomicAdd(p + 1, a1);
            atomicAdd(p + 2, a2); atomicAdd(p + 3, a3);
            a0 = a1 = a2 = a3 = 0.f; gcur = g;
        }
        ushort4 v = *(const ushort4*)&x[(size_t)n * HID + d];
        a0 += bf2f(v.x); a1 += bf2f(v.y); a2 += bf2f(v.z); a3 += bf2f(v.w);
    }
    float* p = &sums[gcur * HID + d];
    atomicAdd(p + 0, a0); atomicAdd(p + 1, a1);
    atomicAdd(p + 2, a2); atomicAdd(p + 3, a3);
}

__device__ __forceinline__ int lowerBound(const int* a, int n, int key) {
    int lo = 0, hi = n;
    while (lo < hi) { int mid = (lo + hi) >> 1; if (a[mid] < key) lo = mid + 1; else hi = mid; }
    return lo;
}

__global__ void k_pool_final(const float* __restrict__ sums, const int* __restrict__ batch,
                             float* __restrict__ out) {
    int g = blockIdx.x, d = threadIdx.x;
    int lo = lowerBound(batch, N_NODES, g);
    int hi = lowerBound(batch, N_NODES, g + 1);
    float cnt = (float)(hi - lo);
    out[(size_t)g * HID + d] = sums[g * HID + d] / fmaxf(cnt, 1.0f);
}

// ---------------- launcher ----------------
extern "C" void kernel_launch(void* const* d_in, const int* in_sizes, int n_in,
                              void* d_out, int out_size, void* d_ws, size_t ws_size,
                              hipStream_t stream) {
    const float* node_feats = (const float*)d_in[0];
    const int*   edge_index = (const int*)d_in[1];
    const int*   batch_idx  = (const int*)d_in[2];
    const float* W_rel0  = (const float*)d_in[3];
    const float* W_root0 = (const float*)d_in[4];
    const float* b0      = (const float*)d_in[5];
    const float* W_rel1  = (const float*)d_in[6];
    const float* W_root1 = (const float*)d_in[7];
    const float* b1      = (const float*)d_in[8];
    const float* W_rel2  = (const float*)d_in[9];
    const float* W_root2 = (const float*)d_in[10];
    const float* b2      = (const float*)d_in[11];
    const float* W_edge  = (const float*)d_in[12];
    const float* b_edge  = (const float*)d_in[13];

    const int* src = edge_index;
    const int* dst = edge_index + N_EDGES;

    char* ws = (char*)d_ws;
    size_t off = 0;
    auto alloc = [&](size_t bytes) -> char* {
        off = (off + 255) & ~(size_t)255;
        char* p = ws + off;
        off += bytes;
        return p;
    };
    unsigned short* bufA = (unsigned short*)alloc((size_t)N_NODES * IN_DIM * 2); // x0b / x2b
    unsigned short* bufB = (unsigned short*)alloc((size_t)N_NODES * HID * 2);    // x1b / x3b
    unsigned short* bufY = (unsigned short*)alloc((size_t)N_NODES * 512 * 2);    // GEMM out bf16
    unsigned short* Wt0  = (unsigned short*)alloc(512 * 512 * 2);
    unsigned short* Wt1  = (unsigned short*)alloc(512 * 256 * 2);
    unsigned short* Wt2  = (unsigned short*)alloc(512 * 256 * 2);
    unsigned short* WeT  = (unsigned short*)alloc(16 * 512 * 2);
    int* counts  = (int*)alloc((size_t)N_NODES * 4);
    int* offsets = (int*)alloc((size_t)(N_NODES + 1) * 4);
    int* cur     = (int*)alloc((size_t)N_NODES * 4);
    int* csr     = (int*)alloc((size_t)N_EDGES * 4);
    int* bsum    = (int*)alloc(512 * 4);
    float* sums  = (float*)alloc(N_GRAPHS * HID * 4);

    const int nscan = (N_NODES + 255) / 256; // 391

    hipMemsetAsync(counts, 0, (size_t)N_NODES * 4, stream);
    hipMemsetAsync(sums, 0, N_GRAPHS * HID * 4, stream);

    // conversions
    k_f2bf<<<(N_NODES * IN_DIM / 8 + 255) / 256, 256, 0, stream>>>(node_feats, bufA, N_NODES * IN_DIM / 8);
    k_makeWt<<<512, 256, 0, stream>>>(W_rel0, W_root0, Wt0, 512);
    k_makeWt<<<512, 256, 0, stream>>>(W_rel1, W_root1, Wt1, 256);
    k_makeWt<<<512, 256, 0, stream>>>(W_rel2, W_root2, Wt2, 256);
    k_makeWeT<<<32, 256, 0, stream>>>(W_edge, WeT);

    // CSR build
    k_hist<<<(N_EDGES + 255) / 256, 256, 0, stream>>>(dst, counts);
    k_scanA<<<nscan, 256, 0, stream>>>(counts, bsum);
    k_scanB<<<1, 256, 0, stream>>>(bsum, nscan);
    k_scanC<<<nscan, 256, 0, stream>>>(counts, bsum, offsets);
    hipMemcpyAsync(cur, offsets, (size_t)N_NODES * 4, hipMemcpyDeviceToDevice, stream);
    k_fill<<<(N_EDGES + 255) / 256, 256, 0, stream>>>(src, dst, cur, csr);

    const int gemmGrid = ((N_NODES + 127) / 128) * 4; // 782*4 = 3128, %8==0
    // layer 0
    k_gemm<<<gemmGrid, 256, 0, stream>>>(bufA, Wt0, bufY, N_NODES, 512);
    k_combine<<<(N_NODES + 3) / 4, 256, 0, stream>>>(bufY, offsets, csr, b0, bufB);
    // layer 1
    k_gemm<<<gemmGrid, 256, 0, stream>>>(bufB, Wt1, bufY, N_NODES, 256);
    k_combine<<<(N_NODES + 3) / 4, 256, 0, stream>>>(bufY, offsets, csr, b1, bufA);
    // layer 2
    k_gemm<<<gemmGrid, 256, 0, stream>>>(bufA, Wt2, bufY, N_NODES, 256);
    k_combine<<<(N_NODES + 3) / 4, 256, 0, stream>>>(bufY, offsets, csr, b2, bufB);

    // edge head -> d_out[0 : 8M)
    float* out_logits = (float*)d_out;
    k_edge<<<(N_EDGES / 16 + 3) / 4, 256, 0, stream>>>(bufB, WeT, src, dst, b_edge, out_logits);

    // mean pool -> d_out[8M : 8M+16384)
    float* out_embed = (float*)d_out + (size_t)N_EDGES * NREL;
    k_pool_sum<<<(N_NODES + 127) / 128, 256, 0, stream>>>(bufB, batch_idx, sums);
    k_pool_final<<<N_GRAPHS, 256, 0, stream>>>(sums, batch_idx, out_embed);
}

// Round 4
// 591.539 us; speedup vs baseline: 1.8690x; 1.1308x over previous
//
#include <hip/hip_runtime.h>

#define N_NODES 100000
#define N_EDGES 500000
#define N_GRAPHS 64
#define IN_DIM 512
#define HID 256
#define NREL 16

using short8 = __attribute__((ext_vector_type(8))) short;
using f32x4  = __attribute__((ext_vector_type(4))) float;

__device__ __forceinline__ unsigned short f2bf(float f) {
    union { float f; unsigned u; } v; v.f = f;
    unsigned u = v.u;
    unsigned r = u + 0x7FFF + ((u >> 16) & 1);
    return (unsigned short)(r >> 16);
}
__device__ __forceinline__ float bf2f(unsigned short h) {
    union { unsigned u; float f; } v; v.u = ((unsigned)h) << 16;
    return v.f;
}

__device__ __forceinline__ void gload_lds16(const unsigned short* g, unsigned short* l) {
    __builtin_amdgcn_global_load_lds(
        (const __attribute__((address_space(1))) void*)(g),
        (__attribute__((address_space(3))) void*)(l), 16, 0, 0);
}

// ---------------- conversions ----------------
__global__ void k_f2bf(const float* __restrict__ in, unsigned short* __restrict__ out, int n8) {
    int i = blockIdx.x * 256 + threadIdx.x;
    if (i >= n8) return;
    const float4* p = (const float4*)in + (size_t)i * 2;
    float4 a = p[0], b = p[1];
    ushort4 u0, u1;
    u0.x = f2bf(a.x); u0.y = f2bf(a.y); u0.z = f2bf(a.z); u0.w = f2bf(a.w);
    u1.x = f2bf(b.x); u1.y = f2bf(b.y); u1.z = f2bf(b.z); u1.w = f2bf(b.w);
    ushort4* q = (ushort4*)out + (size_t)i * 2;
    q[0] = u0; q[1] = u1;
}

// Wt[n][k] = bf16( n<HID ? Wrel[k][n] : Wroot[k][n-HID] ), n in [0,512)
__global__ void k_makeWt(const float* __restrict__ Wrel, const float* __restrict__ Wroot,
                         unsigned short* __restrict__ Wt, int K) {
    int n = blockIdx.x;
    const float* Wsrc = (n < HID) ? Wrel : Wroot;
    int col = n & (HID - 1);
    for (int k = threadIdx.x; k < K; k += 256)
        Wt[(size_t)n * K + k] = f2bf(Wsrc[(size_t)k * HID + col]);
}

// We2T[r][k], r<32, k<256: r<16 -> W_edge[k][r] (src half); r>=16 -> W_edge[256+k][r-16] (dst half)
__global__ void k_makeWe2T(const float* __restrict__ We, unsigned short* __restrict__ We2T) {
    int idx = blockIdx.x * 256 + threadIdx.x;
    if (idx >= 32 * 256) return;
    int r = idx >> 8, k = idx & 255;
    float v = (r < 16) ? We[k * NREL + r] : We[(256 + k) * NREL + (r - 16)];
    We2T[idx] = f2bf(v);
}

// ---------------- CSR build ----------------
__global__ void k_hist(const int* __restrict__ dstArr, int* __restrict__ counts) {
    int i = blockIdx.x * 256 + threadIdx.x;
    if (i < N_EDGES) atomicAdd(&counts[dstArr[i]], 1);
}

__global__ void k_scanA(const int* __restrict__ counts, int* __restrict__ bsum) {
    __shared__ int ws[4];
    int i = blockIdx.x * 256 + threadIdx.x;
    int v = (i < N_NODES) ? counts[i] : 0;
    for (int o = 32; o; o >>= 1) v += __shfl_down(v, o, 64);
    if ((threadIdx.x & 63) == 0) ws[threadIdx.x >> 6] = v;
    __syncthreads();
    if (threadIdx.x == 0) bsum[blockIdx.x] = ws[0] + ws[1] + ws[2] + ws[3];
}

__global__ void k_scanB(int* __restrict__ bsum, int nb) {
    __shared__ int buf[512];
    int t = threadIdx.x;
    for (int i = t; i < nb; i += 256) buf[i] = bsum[i];
    __syncthreads();
    if (t == 0) { int s = 0; for (int i = 0; i < nb; ++i) { int x = buf[i]; buf[i] = s; s += x; } }
    __syncthreads();
    for (int i = t; i < nb; i += 256) bsum[i] = buf[i];
}

__global__ void k_scanC(const int* __restrict__ counts, const int* __restrict__ bsum,
                        int* __restrict__ offsets, int* __restrict__ cur) {
    __shared__ int ws[4];
    int i = blockIdx.x * 256 + threadIdx.x;
    int lane = threadIdx.x & 63, wid = threadIdx.x >> 6;
    int v = (i < N_NODES) ? counts[i] : 0;
    int x = v;
    for (int o = 1; o < 64; o <<= 1) { int u = __shfl_up(x, o, 64); if (lane >= o) x += u; }
    if (lane == 63) ws[wid] = x;
    __syncthreads();
    if (threadIdx.x == 0) { int s = 0; for (int t = 0; t < 4; ++t) { int tt = ws[t]; ws[t] = s; s += tt; } }
    __syncthreads();
    x += ws[wid];
    x += bsum[blockIdx.x];
    if (i < N_NODES) { offsets[i + 1] = x; cur[i] = x - v; }
    if (i == 0) offsets[0] = 0;
}

__global__ void k_fill(const int* __restrict__ srcArr, const int* __restrict__ dstArr,
                       int* __restrict__ cur, int* __restrict__ csr) {
    int i = blockIdx.x * 256 + threadIdx.x;
    if (i < N_EDGES) {
        int p = atomicAdd(&cur[dstArr[i]], 1);
        csr[p] = srcArr[i];
    }
}

// ---------------- GEMM: [Yrel|Yroot][M x 256](bf16) = A[M x K](bf16) @ Bt[512 x K](bf16)^T ----
__global__ __launch_bounds__(256) void k_gemm(const unsigned short* __restrict__ A,
                                              const unsigned short* __restrict__ Bt,
                                              unsigned short* __restrict__ Yrel,
                                              unsigned short* __restrict__ Yroot,
                                              int M, int K) {
    __shared__ unsigned short lds[2 * 128 * 64];
    const int tid  = threadIdx.x;
    const int lane = tid & 63;
    const int w    = tid >> 6;
    const int wm   = w >> 1, wn = w & 1;

    // bijective XCD swizzle (nwg % 8 == 0)
    int nwg  = gridDim.x;
    int orig = blockIdx.x;
    int q    = nwg >> 3;
    int id   = (orig & 7) * q + (orig >> 3);
    int bm0  = (id >> 2) * 128;
    int bn0  = (id & 3) * 128;

    f32x4 acc[4][4] = {};

    const int nkt = K >> 6;
    for (int kt = 0; kt < nkt; ++kt) {
        int k0 = kt << 6;
        #pragma unroll
        for (int it = 0; it < 4; ++it) {
            int c = (it << 8) + tid;
            int row = c >> 3, kcp = c & 7;
            int kcl = kcp ^ (row & 7);
            int gr = bm0 + row; gr = (gr < M) ? gr : (M - 1);
            gload_lds16(A + (size_t)gr * K + k0 + kcl * 8,
                        &lds[(size_t)((it << 8) + (w << 6)) * 8]);
        }
        #pragma unroll
        for (int it = 0; it < 4; ++it) {
            int c = (it << 8) + tid;
            int row = c >> 3, kcp = c & 7;
            int kcl = kcp ^ (row & 7);
            gload_lds16(Bt + (size_t)(bn0 + row) * K + k0 + kcl * 8,
                        &lds[128 * 64 + (size_t)((it << 8) + (w << 6)) * 8]);
        }
        __syncthreads();
        #pragma unroll
        for (int kk = 0; kk < 2; ++kk) {
            short8 af[4], bfr[4];
            #pragma unroll
            for (int m = 0; m < 4; ++m) {
                int row = wm * 64 + m * 16 + (lane & 15);
                int kcp = ((kk << 2) + (lane >> 4)) ^ (row & 7);
                af[m] = *(const short8*)&lds[row * 64 + kcp * 8];
            }
            #pragma unroll
            for (int n = 0; n < 4; ++n) {
                int row = wn * 64 + n * 16 + (lane & 15);
                int kcp = ((kk << 2) + (lane >> 4)) ^ (row & 7);
                bfr[n] = *(const short8*)&lds[128 * 64 + row * 64 + kcp * 8];
            }
            #pragma unroll
            for (int m = 0; m < 4; ++m)
                #pragma unroll
                for (int n = 0; n < 4; ++n)
                    acc[m][n] = __builtin_amdgcn_mfma_f32_16x16x32_bf16(af[m], bfr[n], acc[m][n], 0, 0, 0);
        }
        __syncthreads();
    }
    // epilogue: cols [0,256) -> Yrel, [256,512) -> Yroot (bn0 decides per block)
    unsigned short* Cout = (bn0 < 256) ? Yrel : Yroot;
    int cb = bn0 & 255;
    #pragma unroll
    for (int m = 0; m < 4; ++m) {
        int row0 = bm0 + wm * 64 + m * 16 + ((lane >> 4) << 2);
        #pragma unroll
        for (int n = 0; n < 4; ++n) {
            int col = cb + wn * 64 + n * 16 + (lane & 15);
            #pragma unroll
            for (int i = 0; i < 4; ++i) {
                int r = row0 + i;
                if (r < M) Cout[(size_t)r * 256 + col] = f2bf(acc[m][n][i]);
            }
        }
    }
}

// ---------------- fused aggregate + root + bias + ReLU -> bf16 ----------------
__global__ void k_combine(const unsigned short* __restrict__ yrel,
                          const unsigned short* __restrict__ yroot,
                          const int* __restrict__ offs,
                          const int* __restrict__ csr, const float* __restrict__ bias,
                          unsigned short* __restrict__ xout) {
    int node = blockIdx.x * 4 + (threadIdx.x >> 6);
    if (node >= N_NODES) return;
    int lane = threadIdx.x & 63;
    int d = lane * 4;
    float ax = 0.f, ay = 0.f, az = 0.f, aw = 0.f;
    int j0 = offs[node], j1 = offs[node + 1];
    for (int j = j0; j < j1; ++j) {
        int s = csr[j];
        ushort4 v = *(const ushort4*)(yrel + (size_t)s * 256 + d);
        ax += bf2f(v.x); ay += bf2f(v.y); az += bf2f(v.z); aw += bf2f(v.w);
    }
    ushort4 rr = *(const ushort4*)(yroot + (size_t)node * 256 + d);
    float4 bb = *(const float4*)(bias + d);
    ushort4 pk;
    pk.x = f2bf(fmaxf(ax + bf2f(rr.x) + bb.x, 0.f));
    pk.y = f2bf(fmaxf(ay + bf2f(rr.y) + bb.y, 0.f));
    pk.z = f2bf(fmaxf(az + bf2f(rr.z) + bb.z, 0.f));
    pk.w = f2bf(fmaxf(aw + bf2f(rr.w) + bb.w, 0.f));
    *(ushort4*)(xout + (size_t)node * HID + d) = pk;
}

// ---------------- edge head, stage 1: P[N x 32] = x3 @ We2T^T (fp32 out) ----------------
// P[n][0:16] = x3[n] . We_src ; P[n][16:32] = x3[n] . We_dst
__global__ void k_proj(const unsigned short* __restrict__ x,   // [N][256] bf16
                       const unsigned short* __restrict__ We2T,// [32][256] bf16
                       float* __restrict__ P) {
    int lane = threadIdx.x & 63;
    int g = blockIdx.x * 4 + (threadIdx.x >> 6);   // wave id = 16-node tile
    if (g * 16 >= N_NODES) return;
    int n0 = g * 16;
    short8 bfr[2][8];
    #pragma unroll
    for (int cg = 0; cg < 2; ++cg)
        #pragma unroll
        for (int ks = 0; ks < 8; ++ks)
            bfr[cg][ks] = *(const short8*)&We2T[(size_t)(cg * 16 + (lane & 15)) * 256 + ks * 32 + ((lane >> 4) << 3)];
    f32x4 acc[2] = {};
    const size_t rb = (size_t)(n0 + (lane & 15)) * 256 + ((lane >> 4) << 3);
    #pragma unroll
    for (int ks = 0; ks < 8; ++ks) {
        short8 af = *(const short8*)&x[rb + ks * 32];
        acc[0] = __builtin_amdgcn_mfma_f32_16x16x32_bf16(af, bfr[0][ks], acc[0], 0, 0, 0);
        acc[1] = __builtin_amdgcn_mfma_f32_16x16x32_bf16(af, bfr[1][ks], acc[1], 0, 0, 0);
    }
    #pragma unroll
    for (int cg = 0; cg < 2; ++cg) {
        #pragma unroll
        for (int i = 0; i < 4; ++i) {
            int n = n0 + ((lane >> 4) << 2) + i;
            P[(size_t)n * 32 + cg * 16 + (lane & 15)] = acc[cg][i];
        }
    }
}

// ---------------- edge head, stage 2: out[e] = P[src][0:16] + P[dst][16:32] + b ----------
__global__ void k_edge_add(const float* __restrict__ P,
                           const int* __restrict__ srcArr, const int* __restrict__ dstArr,
                           const float* __restrict__ b_edge, float* __restrict__ out) {
    int e = blockIdx.x * 256 + threadIdx.x;
    if (e >= N_EDGES) return;
    int s = srcArr[e], d = dstArr[e];
    const float4* ps = (const float4*)(P + (size_t)s * 32);
    const float4* pd = (const float4*)(P + (size_t)d * 32 + 16);
    const float4* bb = (const float4*)b_edge;
    float4* po = (float4*)(out + (size_t)e * 16);
    #pragma unroll
    for (int i = 0; i < 4; ++i) {
        float4 a = ps[i], b = pd[i], c = bb[i];
        float4 r;
        r.x = a.x + b.x + c.x; r.y = a.y + b.y + c.y;
        r.z = a.z + b.z + c.z; r.w = a.w + b.w + c.w;
        po[i] = r;
    }
}

// ---------------- mean pool ----------------
__global__ void k_pool_sum(const unsigned short* __restrict__ x, const int* __restrict__ batch,
                           float* __restrict__ sums) {
    const int CH = 32;
    int w = threadIdx.x >> 6, lane = threadIdx.x & 63;
    int n0 = blockIdx.x * (4 * CH) + w * CH;
    if (n0 >= N_NODES) return;
    int n1 = n0 + CH; if (n1 > N_NODES) n1 = N_NODES;
    int d = lane * 4;
    float a0 = 0.f, a1 = 0.f, a2 = 0.f, a3 = 0.f;
    int gcur = batch[n0];
    for (int n = n0; n < n1; ++n) {
        int g = batch[n];
        if (g != gcur) {
            float* p = &sums[gcur * HID + d];
            atomicAdd(p + 0, a0); atomicAdd(p + 1, a1);
            atomicAdd(p + 2, a2); atomicAdd(p + 3, a3);
            a0 = a1 = a2 = a3 = 0.f; gcur = g;
        }
        ushort4 v = *(const ushort4*)&x[(size_t)n * HID + d];
        a0 += bf2f(v.x); a1 += bf2f(v.y); a2 += bf2f(v.z); a3 += bf2f(v.w);
    }
    float* p = &sums[gcur * HID + d];
    atomicAdd(p + 0, a0); atomicAdd(p + 1, a1);
    atomicAdd(p + 2, a2); atomicAdd(p + 3, a3);
}

__device__ __forceinline__ int lowerBound(const int* a, int n, int key) {
    int lo = 0, hi = n;
    while (lo < hi) { int mid = (lo + hi) >> 1; if (a[mid] < key) lo = mid + 1; else hi = mid; }
    return lo;
}

__global__ void k_pool_final(const float* __restrict__ sums, const int* __restrict__ batch,
                             float* __restrict__ out) {
    int g = blockIdx.x, d = threadIdx.x;
    int lo = lowerBound(batch, N_NODES, g);
    int hi = lowerBound(batch, N_NODES, g + 1);
    float cnt = (float)(hi - lo);
    out[(size_t)g * HID + d] = sums[g * HID + d] / fmaxf(cnt, 1.0f);
}

// ---------------- launcher ----------------
extern "C" void kernel_launch(void* const* d_in, const int* in_sizes, int n_in,
                              void* d_out, int out_size, void* d_ws, size_t ws_size,
                              hipStream_t stream) {
    const float* node_feats = (const float*)d_in[0];
    const int*   edge_index = (const int*)d_in[1];
    const int*   batch_idx  = (const int*)d_in[2];
    const float* W_rel0  = (const float*)d_in[3];
    const float* W_root0 = (const float*)d_in[4];
    const float* b0      = (const float*)d_in[5];
    const float* W_rel1  = (const float*)d_in[6];
    const float* W_root1 = (const float*)d_in[7];
    const float* b1      = (const float*)d_in[8];
    const float* W_rel2  = (const float*)d_in[9];
    const float* W_root2 = (const float*)d_in[10];
    const float* b2      = (const float*)d_in[11];
    const float* W_edge  = (const float*)d_in[12];
    const float* b_edge  = (const float*)d_in[13];

    const int* src = edge_index;
    const int* dst = edge_index + N_EDGES;

    char* ws = (char*)d_ws;
    size_t off = 0;
    auto alloc = [&](size_t bytes) -> char* {
        off = (off + 255) & ~(size_t)255;
        char* p = ws + off;
        off += bytes;
        return p;
    };
    unsigned short* bufA  = (unsigned short*)alloc((size_t)N_NODES * IN_DIM * 2); // x0b / x2b
    unsigned short* bufB  = (unsigned short*)alloc((size_t)N_NODES * HID * 2);    // x1b / x3b
    unsigned short* Yrel  = (unsigned short*)alloc((size_t)N_NODES * HID * 2);
    unsigned short* Yroot = (unsigned short*)alloc((size_t)N_NODES * HID * 2);
    unsigned short* Wt0   = (unsigned short*)alloc(512 * 512 * 2);
    unsigned short* Wt1   = (unsigned short*)alloc(512 * 256 * 2);
    unsigned short* Wt2   = (unsigned short*)alloc(512 * 256 * 2);
    unsigned short* We2T  = (unsigned short*)alloc(32 * 256 * 2);
    float* P     = (float*)alloc((size_t)N_NODES * 32 * 4);
    int* counts  = (int*)alloc((size_t)N_NODES * 4);
    int* offsets = (int*)alloc((size_t)(N_NODES + 1) * 4);
    int* cur     = (int*)alloc((size_t)N_NODES * 4);
    int* csr     = (int*)alloc((size_t)N_EDGES * 4);
    int* bsum    = (int*)alloc(512 * 4);
    float* sums  = (float*)alloc(N_GRAPHS * HID * 4);

    const int nscan = (N_NODES + 255) / 256; // 391

    hipMemsetAsync(counts, 0, (size_t)N_NODES * 4, stream);
    hipMemsetAsync(sums, 0, N_GRAPHS * HID * 4, stream);

    // conversions
    k_f2bf<<<(N_NODES * IN_DIM / 8 + 255) / 256, 256, 0, stream>>>(node_feats, bufA, N_NODES * IN_DIM / 8);
    k_makeWt<<<512, 256, 0, stream>>>(W_rel0, W_root0, Wt0, 512);
    k_makeWt<<<512, 256, 0, stream>>>(W_rel1, W_root1, Wt1, 256);
    k_makeWt<<<512, 256, 0, stream>>>(W_rel2, W_root2, Wt2, 256);
    k_makeWe2T<<<32, 256, 0, stream>>>(W_edge, We2T);

    // CSR build
    k_hist<<<(N_EDGES + 255) / 256, 256, 0, stream>>>(dst, counts);
    k_scanA<<<nscan, 256, 0, stream>>>(counts, bsum);
    k_scanB<<<1, 256, 0, stream>>>(bsum, nscan);
    k_scanC<<<nscan, 256, 0, stream>>>(counts, bsum, offsets, cur);
    k_fill<<<(N_EDGES + 255) / 256, 256, 0, stream>>>(src, dst, cur, csr);

    const int gemmGrid = ((N_NODES + 127) / 128) * 4; // 782*4 = 3128, %8==0
    // layer 0
    k_gemm<<<gemmGrid, 256, 0, stream>>>(bufA, Wt0, Yrel, Yroot, N_NODES, 512);
    k_combine<<<(N_NODES + 3) / 4, 256, 0, stream>>>(Yrel, Yroot, offsets, csr, b0, bufB);
    // layer 1
    k_gemm<<<gemmGrid, 256, 0, stream>>>(bufB, Wt1, Yrel, Yroot, N_NODES, 256);
    k_combine<<<(N_NODES + 3) / 4, 256, 0, stream>>>(Yrel, Yroot, offsets, csr, b1, bufA);
    // layer 2
    k_gemm<<<gemmGrid, 256, 0, stream>>>(bufA, Wt2, Yrel, Yroot, N_NODES, 256);
    k_combine<<<(N_NODES + 3) / 4, 256, 0, stream>>>(Yrel, Yroot, offsets, csr, b2, bufB);

    // edge head -> d_out[0 : 8M)
    float* out_logits = (float*)d_out;
    k_proj<<<(N_NODES / 16 + 3) / 4, 256, 0, stream>>>(bufB, We2T, P);
    k_edge_add<<<(N_EDGES + 255) / 256, 256, 0, stream>>>(P, src, dst, b_edge, out_logits);

    // mean pool -> d_out[8M : 8M+16384)
    float* out_embed = (float*)d_out + (size_t)N_EDGES * NREL;
    k_pool_sum<<<(N_NODES + 127) / 128, 256, 0, stream>>>(bufB, batch_idx, sums);
    k_pool_final<<<N_GRAPHS, 256, 0, stream>>>(sums, batch_idx, out_embed);
}